// Round 5
// baseline (260.095 us; speedup 1.0000x reference)
//
#include <hip/hip_runtime.h>
#include <stdint.h>

namespace {
constexpr int N_   = 1024;
constexpr int BND_ = 4;
constexpr int WP_  = N_ + 2 * BND_;   // 1032
constexpr int NN_  = N_ * N_;         // 1<<20

// Counted-vmcnt double-buffered pipeline (guide T3+T4).
// Each 256-thread block walks T_=8 vertical tiles of 128x16 pixels.
// Per iteration:
//   barrier1            (all waves done reading the buffer we re-stage)
//   stage(t+1)  5 DMA   (global_load_lds, fire-and-forget)
//   fence; vec(t+1) 4   (float4 register loads)
//   s_waitcnt vmcnt(K)  (ONLY tile-t DMAs -- issued a full phase ago)
//   barrier2            (all waves' tile-t staging visible)
//   compute(t)          (scattered ds_reads + 4 float2 stores, never waited)
// R3's vmcnt(0) drain stalled every phase on store-acks + DMA tails; the
// counted wait lets stores and next-tile DMAs stay in flight (m218: counted
// vs drain-0 was +38-73% on GEMM). vmcnt retires FIFO (m135), so fallback
// loads issued during compute only make the counted waits conservative.
constexpr int TW_ = 128;              // tile width
constexpr int TH_ = 16;               // tile height
constexpr int T_  = 8;                // tiles walked per block (128 rows)
constexpr int CW_ = 144;              // staged window cols = 36 float4/row
constexpr int CH_ = 32;               // staged window rows
constexpr int NV_ = (CW_ / 4) * CH_;  // 1152 16B chunks per window
constexpr int HALO_ = 8;
constexpr int GROUPS_Y = N_ / (TH_ * T_);            // 8
constexpr int TILES_PER_IMG = (N_ / TW_) * GROUPS_Y; // 64 blocks/image

// vmcnt-counting contract: every thread issues EXACTLY 5 gload_lds per
// stage (uniform per wave), then 4 vec loads, then 4 stores per compute.
// Ops newer than tile-t's DMAs at the wait point:
//   steady: vec(t)4 + stores(t-1)4 + stage(t+1)5 + vec(t+1)4 = 17
//   t=0   : vec(0)4 + stage(1)5 + vec(1)4               = 13
//   t=T-1 : vec(T-1)4 + stores(T-2)4                    = 8
// Fallback global loads in compute only ADD newer ops -> waits stay safe.

// Exact replication of reference gather (rare fallback: border pixels /
// |v| beyond the staged halo): clip flat index into padded (WP x WP) sdf,
// then pad value 1.0 or interior grid value.
__device__ __forceinline__ float fetch_pad(const float* __restrict__ gb, int idx) {
    idx = min(max(idx, 0), WP_ * WP_ - 1);
    int yy = idx / WP_;
    int xx = idx - yy * WP_;
    if (xx >= BND_ && xx < WP_ - BND_ && yy >= BND_ && yy < WP_ - BND_)
        return gb[(yy - BND_) * N_ + (xx - BND_)];
    return 1.0f;
}

__device__ __forceinline__ void gload_lds16(const float* g, float* l) {
    __builtin_amdgcn_global_load_lds(
        (const __attribute__((address_space(1))) void*)(uintptr_t)g,
        (__attribute__((address_space(3))) void*)(uint32_t)(uintptr_t)l,
        16, 0, 0);
}

__device__ __forceinline__ void barrier_fenced() {
    asm volatile("" ::: "memory");
    __builtin_amdgcn_s_barrier();
    asm volatile("" ::: "memory");
}

// Stage one 144x32 window: 1152 chunks. u=0..3 cover chunks 0..1023
// (4/thread); u=4 covers 1024..1151 issued by ALL threads (tid&127) so
// every wave issues exactly 5 DMA instructions -- threads 128..255
// redundantly rewrite the same chunks with identical data (benign).
__device__ __forceinline__ void stage_tile(const float* src0, float* buf, int tid) {
#pragma unroll
    for (int u = 0; u < 4; ++u) {
        int e  = tid + u * 256;
        int r  = e / (CW_ / 4);
        int c4 = e - r * (CW_ / 4);
        gload_lds16(src0 + (size_t)r * N_ + 4 * c4, buf + 4 * e);
    }
    {
        int e  = (tid & 127) + 1024;
        int r  = e / (CW_ / 4);
        int c4 = e - r * (CW_ / 4);
        gload_lds16(src0 + (size_t)r * N_ + 4 * c4, buf + 4 * e);
    }
}

__device__ __forceinline__ void load_vec(float4* pv, const float* __restrict__ vec,
                                         size_t vb, int jt, int rr, int i0) {
#pragma unroll
    for (int s = 0; s < 4; ++s) {
        int j = jt + rr + 4 * s;
        pv[s] = *reinterpret_cast<const float4*>(vec + 2 * (vb + (size_t)j * N_ + i0));
    }
}
} // namespace

__global__ __launch_bounds__(256, 4) void advect_kernel(
    const float* __restrict__ grid,   // (B,N,N) fp32
    const float* __restrict__ vec,    // (B,N,N,2) fp32
    float* __restrict__ out)          // (B,N,N) fp32
{
    __shared__ float sg[2][CW_ * CH_];   // 2 x 18432 B

    int bid = blockIdx.x;
    int b   = bid >> 6;               // / TILES_PER_IMG (64)
    int r6  = bid & 63;
    int tyg = r6 >> 3;                // vertical group 0..7
    int txi = r6 & 7;
    int it  = txi * TW_;
    int jt0 = tyg * (TH_ * T_);       // first tile row of this block

    const float* gb = grid + (size_t)b * NN_;
    size_t vb = (size_t)b * NN_;
    int tid = threadIdx.x;
    int cp  = tid & 63;               // column-pair 0..63 (wave-contiguous)
    int rr  = tid >> 6;               // wave id 0..3 -> row offset
    int i0  = it + 2 * cp;

    // Window x-origin, clamped into the image (multiple of 4 -> 16B-aligned).
    int gi0 = min(max(it - HALO_, 0), N_ - CW_);

    // ---- Prologue: stage tile 0 (5 DMA), then its vec (order pinned) ----
    {
        int gj0 = min(max(jt0 - HALO_, 0), N_ - CH_);
        stage_tile(gb + (size_t)gj0 * N_ + gi0, sg[0], tid);
    }
    asm volatile("" ::: "memory");        // pin: DMAs before vec loads
    float4 pv[4];
    load_vec(pv, vec, vb, jt0, rr, i0);

    // ---- Pipelined tile walk ----
#pragma unroll
    for (int t = 0; t < T_; ++t) {
        int jt  = jt0 + t * TH_;
        int gj0 = min(max(jt - HALO_, 0), N_ - CH_);

        // barrier1: every wave finished its ds_reads of buf[(t+1)&1]
        // (= buffer read during compute(t-1)) before we overwrite it.
        barrier_fenced();

        float4 pvn[4];
        if (t + 1 < T_) {
            int jtn  = jt + TH_;
            int gj0n = min(max(jtn - HALO_, 0), N_ - CH_);
            stage_tile(gb + (size_t)gj0n * N_ + gi0, sg[(t + 1) & 1], tid);
            asm volatile("" ::: "memory"); // pin: DMAs before vec loads
            load_vec(pvn, vec, vb, jtn, rr, i0);
        }

        // Counted wait: only tile-t's 5 DMAs (issued one full phase ago)
        // must have landed. Stores and tile-(t+1) traffic stay in flight.
        if (t == 0)
            asm volatile("s_waitcnt vmcnt(13)" ::: "memory");
        else if (t + 1 < T_)
            asm volatile("s_waitcnt vmcnt(17)" ::: "memory");
        else
            asm volatile("s_waitcnt vmcnt(8)" ::: "memory");
        // barrier2: all waves' tile-t staging visible before any ds_read.
        barrier_fenced();

        const float* sb = sg[t & 1];
#pragma unroll
        for (int s = 0; s < 4; ++s) {
            int j = jt + rr + 4 * s;
            float r2[2];
#pragma unroll
            for (int h = 0; h < 2; ++h) {
                int   i  = i0 + h;
                float vx = h ? pv[s].z : pv[s].x;
                float vy = h ? pv[s].w : pv[s].y;
                // fp32 op order must match numpy: ((i+0.5) - vx) + 3.5
                float px = ((float)i + 0.5f - vx) + 3.5f;
                float py = ((float)j + 0.5f - vy) + 3.5f;
                int x = (int)px;      // trunc toward zero == astype(int32)
                int y = (int)py;
                float fx = px - (float)x;
                float fy = py - (float)y;

                int lx = (x - BND_) - gi0;
                int ly = (y - BND_) - gj0;

                float g00, g01, g10, g11;
                if (lx >= 0 && lx <= CW_ - 2 && ly >= 0 && ly <= CH_ - 2) {
                    const float* p = &sb[ly * CW_ + lx];
                    g00 = p[0];
                    g01 = p[1];
                    g10 = p[CW_];
                    g11 = p[CW_ + 1];
                } else {
                    int idx = x + y * WP_;
                    g00 = fetch_pad(gb, idx);
                    g01 = fetch_pad(gb, idx + 1);
                    g10 = fetch_pad(gb, idx + WP_);
                    g11 = fetch_pad(gb, idx + WP_ + 1);
                }
                r2[h] = g00 * (1.0f - fx) * (1.0f - fy)
                      + g01 * fx          * (1.0f - fy)
                      + g10 * (1.0f - fx) * fy
                      + g11 * fx          * fy;
            }
            float2 st;
            st.x = r2[0];
            st.y = r2[1];
            *reinterpret_cast<float2*>(out + vb + (size_t)j * N_ + i0) = st;
        }

        if (t + 1 < T_) {
#pragma unroll
            for (int q = 0; q < 4; ++q) pv[q] = pvn[q];
        }
    }
}

extern "C" void kernel_launch(void* const* d_in, const int* in_sizes, int n_in,
                              void* d_out, int out_size, void* d_ws, size_t ws_size,
                              hipStream_t stream)
{
    const float* grid = (const float*)d_in[0];
    const float* vec  = (const float*)d_in[1];
    float* out = (float*)d_out;

    int total  = in_sizes[0];                     // B*N*N
    int nB     = total / NN_;                     // 16
    int blocks = nB * TILES_PER_IMG;              // 1024
    advect_kernel<<<blocks, 256, 0, stream>>>(grid, vec, out);
}

// Round 6
// 248.015 us; speedup vs baseline: 1.0487x; 1.0487x over previous
//
#include <hip/hip_runtime.h>
#include <stdint.h>

namespace {
constexpr int N_   = 1024;
constexpr int BND_ = 4;
constexpr int WP_  = N_ + 2 * BND_;   // 1032
constexpr int NN_  = N_ * N_;         // 1<<20

// Max-occupancy single-tile design. R1-R5 showed all barrier-coupled
// pipeline variants stuck at ~95 us with every pipe ~20% busy ->
// latency-bound at low occupancy. Fix: many small INDEPENDENT blocks.
// 256-thread block = one 128x16 tile, 18.4 KB LDS window -> 8 blocks/CU
// (100% wave occupancy). Block A's staging drain hides under blocks B..H's
// compute (m114 implicit wave-level overlap) -- no intra-kernel pipeline.
constexpr int TW_ = 128;              // tile width
constexpr int TH_ = 16;               // tile height
constexpr int CW_ = 144;              // staged window cols = 36 float4/row
constexpr int CH_ = 32;               // staged window rows
constexpr int NV_ = (CW_ / 4) * CH_;  // 1152 16B chunks
constexpr int HALO_ = 8;
constexpr int TILES_PER_IMG = (N_ / TW_) * (N_ / TH_);  // 512

// Two x-adjacent taps are contiguous dwords in LDS; a 4B-aligned 8B vector
// load lets LLVM emit ds_read2_b32 -> 2 LDS instrs/pixel instead of 4.
typedef float float2a __attribute__((ext_vector_type(2), aligned(4)));

// Exact replication of reference gather (rare fallback: border pixels /
// |v| beyond the staged halo): clip flat index into padded (WP x WP) sdf,
// then pad value 1.0 or interior grid value.
__device__ __forceinline__ float fetch_pad(const float* __restrict__ gb, int idx) {
    idx = min(max(idx, 0), WP_ * WP_ - 1);
    int yy = idx / WP_;
    int xx = idx - yy * WP_;
    if (xx >= BND_ && xx < WP_ - BND_ && yy >= BND_ && yy < WP_ - BND_)
        return gb[(yy - BND_) * N_ + (xx - BND_)];
    return 1.0f;
}

__device__ __forceinline__ void gload_lds16(const float* g, float* l) {
    __builtin_amdgcn_global_load_lds(
        (const __attribute__((address_space(1))) void*)(uintptr_t)g,
        (__attribute__((address_space(3))) void*)(uint32_t)(uintptr_t)l,
        16, 0, 0);
}
} // namespace

__global__ __launch_bounds__(256, 8) void advect_kernel(
    const float* __restrict__ grid,   // (B,N,N) fp32
    const float* __restrict__ vec,    // (B,N,N,2) fp32
    float* __restrict__ out)          // (B,N,N) fp32
{
    __shared__ float sg[CW_ * CH_];   // 18432 B -> 8 blocks/CU

    int bid = blockIdx.x;
    int b   = bid >> 9;               // / TILES_PER_IMG (512)
    int t   = bid & 511;
    int tyi = t >> 3;                 // 0..63
    int txi = t & 7;
    int it  = txi * TW_;
    int jt  = tyi * TH_;

    const float* gb = grid + (size_t)b * NN_;
    size_t vb = (size_t)b * NN_;
    int tid = threadIdx.x;
    int cp  = tid & 63;               // column-pair 0..63 (wave-contiguous)
    int rr  = tid >> 6;               // wave id 0..3 -> row offset
    int i0  = it + 2 * cp;

    // Clamped window origin (gi0 multiple of 4 -> 16B-aligned rows).
    int gi0 = min(max(it - HALO_, 0), N_ - CW_);
    int gj0 = min(max(jt - HALO_, 0), N_ - CH_);

    // ---- Stage 144x32 window: 1152 chunks, 4/thread + tail by tid<128 ----
    {
        const float* src0 = gb + (size_t)gj0 * N_ + gi0;
#pragma unroll
        for (int u = 0; u < 4; ++u) {
            int e  = tid + u * 256;
            int r  = e / (CW_ / 4);
            int c4 = e - r * (CW_ / 4);
            gload_lds16(src0 + (size_t)r * N_ + 4 * c4, &sg[4 * e]);
        }
        if (tid < 128) {
            int e  = 1024 + tid;
            int r  = e / (CW_ / 4);
            int c4 = e - r * (CW_ / 4);
            gload_lds16(src0 + (size_t)r * N_ + 4 * c4, &sg[4 * e]);
        }
    }

    // ---- Prefetch the 8 displacement vectors (4 x float4, coalesced) ----
    float4 pv[4];
#pragma unroll
    for (int s = 0; s < 4; ++s) {
        int j = jt + rr + 4 * s;
        pv[s] = *reinterpret_cast<const float4*>(vec + 2 * (vb + (size_t)j * N_ + i0));
    }
#pragma unroll
    for (int q = 0; q < 4; ++q)
        asm volatile("" : "+v"(pv[q].x), "+v"(pv[q].y), "+v"(pv[q].z), "+v"(pv[q].w));

    __syncthreads();   // drains staging DMAs; stall hidden by other 7 blocks/CU

    // ---- Compute 8 pixels: 4 rows x 2 adjacent columns ----
#pragma unroll
    for (int s = 0; s < 4; ++s) {
        int j = jt + rr + 4 * s;
        float r2[2];
#pragma unroll
        for (int h = 0; h < 2; ++h) {
            int   i  = i0 + h;
            float vx = h ? pv[s].z : pv[s].x;
            float vy = h ? pv[s].w : pv[s].y;
            // fp32 op order must match numpy: ((i+0.5) - vx) + 3.5
            float px = ((float)i + 0.5f - vx) + 3.5f;
            float py = ((float)j + 0.5f - vy) + 3.5f;
            int x = (int)px;          // trunc toward zero == astype(int32)
            int y = (int)py;
            float fx = px - (float)x;
            float fy = py - (float)y;

            int lx = (x - BND_) - gi0;
            int ly = (y - BND_) - gj0;

            float g00, g01, g10, g11;
            if (lx >= 0 && lx <= CW_ - 2 && ly >= 0 && ly <= CH_ - 2) {
                const float* p = &sg[ly * CW_ + lx];
                float2a t0 = *reinterpret_cast<const float2a*>(p);        // ds_read2_b32
                float2a t1 = *reinterpret_cast<const float2a*>(p + CW_);  // ds_read2_b32
                g00 = t0.x; g01 = t0.y;
                g10 = t1.x; g11 = t1.y;
            } else {
                int idx = x + y * WP_;
                g00 = fetch_pad(gb, idx);
                g01 = fetch_pad(gb, idx + 1);
                g10 = fetch_pad(gb, idx + WP_);
                g11 = fetch_pad(gb, idx + WP_ + 1);
            }
            r2[h] = g00 * (1.0f - fx) * (1.0f - fy)
                  + g01 * fx          * (1.0f - fy)
                  + g10 * (1.0f - fx) * fy
                  + g11 * fx          * fy;
        }
        float2 st;
        st.x = r2[0];
        st.y = r2[1];
        *reinterpret_cast<float2*>(out + vb + (size_t)j * N_ + i0) = st;
    }
}

extern "C" void kernel_launch(void* const* d_in, const int* in_sizes, int n_in,
                              void* d_out, int out_size, void* d_ws, size_t ws_size,
                              hipStream_t stream)
{
    const float* grid = (const float*)d_in[0];
    const float* vec  = (const float*)d_in[1];
    float* out = (float*)d_out;

    int total  = in_sizes[0];                     // B*N*N
    int nB     = total / NN_;                     // 16
    int blocks = nB * TILES_PER_IMG;              // 8192
    advect_kernel<<<blocks, 256, 0, stream>>>(grid, vec, out);
}